// Round 12
// baseline (121.456 us; speedup 1.0000x reference)
//
#include <hip/hip_runtime.h>
#include <hip/hip_bf16.h>

typedef __bf16 bf16x8 __attribute__((ext_vector_type(8)));
typedef float f32x4 __attribute__((ext_vector_type(4)));

#define MFMA16 __builtin_amdgcn_mfma_f32_16x16x32_bf16

__device__ __forceinline__ unsigned short f2b(float f) {
  unsigned int u = __float_as_uint(f);
  u += 0x7FFFu + ((u >> 16) & 1u);
  return (unsigned short)(u >> 16);
}

__device__ __forceinline__ float b2f(unsigned short s) {
  return __uint_as_float(((unsigned)s) << 16);
}

union U128 {
  uint4 u;
  unsigned short s[8];
  bf16x8 b;
};

union BPack {
  __hip_bfloat162 h2;
  unsigned u;
};

__device__ __forceinline__ unsigned packbf(float a, float b) {
  BPack p;
  p.h2 = __float22bfloat162_rn(make_float2(a, b));
  return p.u;
}

// ---------------- projection via MFMA (unchanged, proven ~3 us) ------------
// grid 512 = (b = blk&7, n0 = 64-tile). block 256 (4 waves).
// wq rows pre-scaled by log2(e) so attention uses native exp2.
// h stored BLOCKED: h_blk[b][n>>3][c][n&7].
__global__ __launch_bounds__(256, 2) void proj_kernel(
    const float* __restrict__ x, const float* __restrict__ wq,
    const float* __restrict__ wk, const float* __restrict__ wv_w,
    unsigned short* __restrict__ f_t, unsigned short* __restrict__ g_t,
    unsigned short* __restrict__ h_out) {
  __shared__ unsigned short xT[64 * 64];
  __shared__ unsigned short wT[96 * 72];

  const int tid = (int)threadIdx.x;
  const int wvp = tid >> 6;
  const int lane = tid & 63;
  const int b = (int)blockIdx.x & 7;
  const int n0 = ((int)blockIdx.x >> 3) << 6;

  {
    const float* xb = x + ((size_t)b << 18) + n0 + lane;
    const int c0 = wvp * 16;
    float xv[16];
#pragma unroll
    for (int cc = 0; cc < 16; ++cc) xv[cc] = xb[(size_t)(c0 + cc) << 12];
#pragma unroll
    for (int p = 0; p < 4; ++p) {
      const int c = c0 + 4 * p;
      uint2 d;
      d.x = packbf(xv[4 * p + 0], xv[4 * p + 1]);
      d.y = packbf(xv[4 * p + 2], xv[4 * p + 3]);
      const int g = c >> 3;
      const int idx = lane * 64 + (((g ^ (lane & 7)) << 3) | (((c >> 2) & 1) << 2));
      *(uint2*)&xT[idx] = d;
    }
  }
#pragma unroll
  for (int i = 0; i < 20; ++i) {
    const int idx = i * 256 + tid;
    const float wval = (idx < 512) ? wq[idx] * 1.44269504f
                     : (idx < 1024) ? wk[idx - 512]
                                    : wv_w[idx - 1024];
    wT[(idx >> 6) * 72 + (idx & 63)] = f2b(wval);
  }
  __syncthreads();

  const int t = lane & 15, q = lane >> 4;
  const int nloc = wvp * 16 + t;
  U128 Bf[2];
#pragma unroll
  for (int kp = 0; kp < 2; ++kp) {
    const int g = kp * 4 + q;
    Bf[kp].u = *(const uint4*)&xT[nloc * 64 + ((g ^ (nloc & 7)) << 3)];
  }
  const int nabs = n0 + nloc;
#pragma unroll
  for (int rt = 0; rt < 5; ++rt) {
    f32x4 acc = {0.f, 0.f, 0.f, 0.f};
#pragma unroll
    for (int kp = 0; kp < 2; ++kp) {
      U128 Af;
      Af.u = *(const uint4*)&wT[(rt * 16 + t) * 72 + ((kp * 4 + q) << 3)];
      acc = MFMA16(Af.b, Bf[kp].b, acc, 0, 0, 0);
    }
#pragma unroll
    for (int reg = 0; reg < 4; ++reg) {
      const int r = rt * 16 + 4 * q + reg;
      const unsigned short v = f2b(acc[reg]);
      if (r < 8)
        f_t[((size_t)((b << 12) + nabs) << 3) + r] = v;
      else if (r < 16)
        g_t[((size_t)((b << 12) + nabs) << 3) + (r - 8)] = v;
      else
        h_out[((size_t)b << 18) + ((size_t)(nabs >> 3) << 9) +
              ((r - 16) << 3) + (nabs & 7)] = v;
    }
  }
}

// ---------------- flash attention: m16 waves, 16x16 MFMA, 6 waves/SIMD -----
// grid 2048 = (b = blk&7, m16-tile). block 256 (4 waves), wave = n-quarter.
// Per 32-n iter: 2 score MFMA16 (S[n16][m16], K 8->32 zero-G-padded), 8 exp2,
// 4 packs, C->B transform via 8 ds_bpermute + 4 hh-selects, 4 PV MFMA16
// (O[c16-tile][m16], 16 AGPRs total). ~76 regs -> 6 waves/SIMD (24/CU) vs
// the 32x32 variant's 4. Transform derivation: B-frag dword p of lane(t,q)
// = dword (p&1) of lane t+16*(2(q&1)+(p>>1)), subtile q>>1.
__global__ __launch_bounds__(256, 6) void attn_kernel(
    const unsigned short* __restrict__ f_t, const unsigned short* __restrict__ g_t,
    const unsigned short* __restrict__ h, const float* __restrict__ x,
    const float* __restrict__ gamma, float* __restrict__ out) {
  __shared__ unsigned short Opart[4][16][66];  // [wave][m][c] bf16, 8.25 KB
  __shared__ float lred[4][16];
  __shared__ float lsum[16];

  const int tid = (int)threadIdx.x;
  const int wave = tid >> 6;
  const int lane = tid & 63;
  const int t = lane & 15;
  const int q = lane >> 4;
  const int hh = lane >> 5;  // subtile select for the transform

  const int b = (int)blockIdx.x & 7;
  const int m0 = ((int)blockIdx.x >> 3) << 4;

  const unsigned short* fb = f_t + ((size_t)b << 15);
  const unsigned short* hb = h + ((size_t)b << 18);  // blocked layout

  // G fragment: B[k][m=t], k=8q+j; valid only q==0 (K padded 8->32)
  U128 G;
  G.u = make_uint4(0u, 0u, 0u, 0u);
  if (q == 0) G.u = *(const uint4*)(g_t + ((size_t)((b << 12) + m0 + t) << 3));

  f32x4 O0 = {}, O1 = {}, O2 = {}, O3 = {};
  float lp = 0.f;

  // bpermute byte-indices (constant): source lanes t+16*2(q&1), +16
  const int bpa = (t + (((q & 1) << 1) << 4)) << 2;
  const int bpb = bpa + 64;

  const int nbase = wave << 10;

  for (int it = 0; it < 32; ++it) {
    const int n32 = nbase + (it << 5);

    // H A-fragments, 4 c-tiles: A[c=16ct+t][k=n32+8q+j]
    const unsigned short* hg = hb + ((size_t)n32 << 6) + (q << 9) + (t << 3);
    U128 H0, H1, H2, H3;
    H0.u = *(const uint4*)(hg);
    H1.u = *(const uint4*)(hg + 128);
    H2.u = *(const uint4*)(hg + 256);
    H3.u = *(const uint4*)(hg + 384);

    // F A-fragments (two n16 subtiles): A[n=t][k], k<8 valid (G zeros rest)
    U128 F0, F1;
    F0.u = *(const uint4*)(fb + ((size_t)(n32 + t) << 3));
    F1.u = *(const uint4*)(fb + ((size_t)(n32 + 16 + t) << 3));

    const f32x4 z4 = {0.f, 0.f, 0.f, 0.f};
    f32x4 S0 = MFMA16(F0.b, G.b, z4, 0, 0, 0);
    f32x4 S1 = MFMA16(F1.b, G.b, z4, 0, 0, 0);

    // exp + denominator + pack (C-layout: lane holds rows 4q+r, col t)
    float e0 = __builtin_amdgcn_exp2f(S0[0]);
    float e1 = __builtin_amdgcn_exp2f(S0[1]);
    float e2 = __builtin_amdgcn_exp2f(S0[2]);
    float e3 = __builtin_amdgcn_exp2f(S0[3]);
    float e4 = __builtin_amdgcn_exp2f(S1[0]);
    float e5 = __builtin_amdgcn_exp2f(S1[1]);
    float e6 = __builtin_amdgcn_exp2f(S1[2]);
    float e7 = __builtin_amdgcn_exp2f(S1[3]);
    lp += ((e0 + e1) + (e2 + e3)) + ((e4 + e5) + (e6 + e7));

    const int d00 = (int)packbf(e0, e1);  // subtile0 rows 4q+0,1
    const int d01 = (int)packbf(e2, e3);  // subtile0 rows 4q+2,3
    const int d10 = (int)packbf(e4, e5);  // subtile1
    const int d11 = (int)packbf(e6, e7);

    // C->B: 8 bpermutes; consumer picks its subtile by hh
    const int p0a = __builtin_amdgcn_ds_bpermute(bpa, d00);
    const int p0b = __builtin_amdgcn_ds_bpermute(bpa, d01);
    const int p0c = __builtin_amdgcn_ds_bpermute(bpb, d00);
    const int p0d = __builtin_amdgcn_ds_bpermute(bpb, d01);
    const int p1a = __builtin_amdgcn_ds_bpermute(bpa, d10);
    const int p1b = __builtin_amdgcn_ds_bpermute(bpa, d11);
    const int p1c = __builtin_amdgcn_ds_bpermute(bpb, d10);
    const int p1d = __builtin_amdgcn_ds_bpermute(bpb, d11);

    U128 P;
    P.u.x = (unsigned)(hh ? p1a : p0a);
    P.u.y = (unsigned)(hh ? p1b : p0b);
    P.u.z = (unsigned)(hh ? p1c : p0c);
    P.u.w = (unsigned)(hh ? p1d : p0d);

    O0 = MFMA16(H0.b, P.b, O0, 0, 0, 0);
    O1 = MFMA16(H1.b, P.b, O1, 0, 0, 0);
    O2 = MFMA16(H2.b, P.b, O2, 0, 0, 0);
    O3 = MFMA16(H3.b, P.b, O3, 0, 0, 0);
  }

  // denominator: lane(t,q) holds partial for col t; combine 4 quads
  lp += __shfl_xor(lp, 16, 64);
  lp += __shfl_xor(lp, 32, 64);
  if (lane < 16) lred[wave][t] = lp;

  // stash O partials (C-layout: c = 16ct + 4q + r, m = t) as bf16 pairs
#pragma unroll
  for (int ct = 0; ct < 4; ++ct) {
    const f32x4 Ov = (ct == 0) ? O0 : (ct == 1) ? O1 : (ct == 2) ? O2 : O3;
    const int cb = 16 * ct + 4 * q;
    *(unsigned*)&Opart[wave][t][cb] = packbf(Ov[0], Ov[1]);
    *(unsigned*)&Opart[wave][t][cb + 2] = packbf(Ov[2], Ov[3]);
  }
  __syncthreads();
  if (tid < 16)
    lsum[tid] = (lred[0][tid] + lred[1][tid]) + (lred[2][tid] + lred[3][tid]);
  __syncthreads();

  // epilogue: thread owns c = tid>>2, m = m0 + (tid&3)*4 .. +4
  const int c = tid >> 2;
  const int ms = (tid & 3) << 2;
  const float gam = gamma[0];
  float a[4];
#pragma unroll
  for (int j = 0; j < 4; ++j) a[j] = 0.f;
#pragma unroll
  for (int w = 0; w < 4; ++w)
#pragma unroll
    for (int j = 0; j < 4; ++j) a[j] += b2f(Opart[w][ms + j][c]);

  const f32x4 lv = *(const f32x4*)&lsum[ms];
  const size_t oi = (((size_t)b * 64 + c) << 12) + m0 + ms;
  f32x4 xo = *(const f32x4*)(x + oi);
#pragma unroll
  for (int j = 0; j < 4; ++j) xo[j] += gam / lv[j] * a[j];
  *(f32x4*)(out + oi) = xo;
}

extern "C" void kernel_launch(void* const* d_in, const int* in_sizes, int n_in,
                              void* d_out, int out_size, void* d_ws, size_t ws_size,
                              hipStream_t stream) {
  (void)in_sizes; (void)n_in; (void)out_size; (void)ws_size;
  const float* x = (const float*)d_in[0];
  const float* wq = (const float*)d_in[1];
  const float* wk = (const float*)d_in[2];
  const float* wv = (const float*)d_in[3];
  const float* gamma = (const float*)d_in[4];
  float* out = (float*)d_out;

  // workspace: f_t [8][4096][8] bf16, g_t same, h_blk [8][512][64][8] bf16
  unsigned short* f_t = (unsigned short*)d_ws;
  unsigned short* g_t = f_t + (size_t)8 * 4096 * 8;
  unsigned short* h = g_t + (size_t)8 * 4096 * 8;

  proj_kernel<<<512, 256, 0, stream>>>(x, wq, wk, wv, f_t, g_t, h);
  attn_kernel<<<2048, 256, 0, stream>>>(f_t, g_t, h, x, gamma, out);
}